// Round 11
// baseline (135.626 us; speedup 1.0000x reference)
//
#include <hip/hip_runtime.h>
#include <cmath>

namespace {

using bf16x8 = __attribute__((ext_vector_type(8))) short;
using f32x4  = __attribute__((ext_vector_type(4))) float;

constexpr int NT = 192;        // 3 waves per block
constexpr int NS = 16;         // samples per tile (one MFMA M-tile)
constexpr int TILE_BYTES = NS * 31 * 32 * 2;  // 31744 B (LPAD=31)
constexpr int B = 16384;
constexpr int T = 4;           // tiles per block (double-buffered pipeline)
constexpr int ITEMS = 8;       // stage items per thread (covers 64*23/192)

__device__ __forceinline__ short f2bf(float f) {  // RNE float->bf16
  unsigned u = __float_as_uint(f);
  return (short)((u + 0x7FFFu + ((u >> 16) & 1u)) >> 16);
}

// Granule index for tile[s][q][cq*8..+7]. Bijective: only permutes cq within
// the (s,q) quad (blocks 4u..4u+3 disjoint). Proven correct+fast since r3.
__device__ __forceinline__ int gidx(int s, int q, int cq) {
  return (s * 31 + q) * 4 + ((cq ^ ((s >> 1) + (q >> 1))) & 3);
}

__device__ __forceinline__ bf16x8 ldcol(const char* buf, int s, int cq, int q) {
  return *(const bf16x8*)(buf + (gidx(s, q, cq) << 4));
}

// ---- async staging: issue loads early (regs), write to LDS late ----
struct StageRegs {
  float v[ITEMS][8];
  int   off[ITEMS];   // swizzled LDS byte offset, -1 = inactive
};

__device__ __forceinline__ void stage_issue(const float* __restrict__ xi, int L,
                                            int b0, int tid, StageRegs& sr) {
  int l  = tid % L;          // one div; then incremental (no div per item)
  int rr = tid / L;
  const int qd = NT / L, rd = NT % L;
  #pragma unroll
  for (int u = 0; u < ITEMS; ++u) {
    sr.off[u] = -1;
    if (u * NT + tid < 64 * L) {
      const int cg = rr & 3;
      const int ss = rr >> 2;
      const float* src = xi + ((size_t)(b0 + ss) * 32 + cg * 8) * L + l;
      #pragma unroll
      for (int j = 0; j < 8; ++j) sr.v[u][j] = src[(size_t)j * L];
      sr.off[u] = gidx(ss, l + 4, cg) << 4;
    }
    l += rd; rr += qd;
    if (l >= L) { l -= L; rr += 1; }
  }
}

__device__ __forceinline__ void stage_write(char* __restrict__ buf, const StageRegs& sr) {
  #pragma unroll
  for (int u = 0; u < ITEMS; ++u) {
    if (sr.off[u] >= 0) {
      bf16x8 pk;
      #pragma unroll
      for (int j = 0; j < 8; ++j) pk[j] = f2bf(sr.v[u][j]);
      *(bf16x8*)(buf + sr.off[u]) = pk;
    }
  }
}

// ---- compute one tile for one role (weights already in regs) ----
template<int K1, int K2>
__device__ __forceinline__ f32x4 compute_tile(
    const char* __restrict__ buf, int s, int cq, int L,
    const bf16x8 (&wf1)[K1], const bf16x8 (&wf2)[(K2 > 0) ? K2 : 1],
    float b1, float b2, float dv1, float dv2)
{
  constexpr int KK1 = (K1 - 1) / 2;
  constexpr int KK2 = (K2 > 0) ? (K2 - 1) / 2 : 0;
  constexpr int NCH = (K1 >= 7) ? 3 : 2;   // accumulator chains (ILP)

  f32x4 mx1 = {0.f, 0.f, 0.f, 0.f};   // ReLU folded into max-init 0
  f32x4 mx2 = {0.f, 0.f, 0.f, 0.f};

  // Sliding window invariant: af[(P+t)%K1] holds padded col P + 4 - KK1 + t.
  bf16x8 af[K1];
  #pragma unroll
  for (int j = 0; j < K1; ++j) af[j] = ldcol(buf, s, cq, 4 - KK1 + j);

  auto body = [&](int p, int pi) {
    f32x4 ca = {b1, b1, b1, b1};
    f32x4 cb = {0.f, 0.f, 0.f, 0.f};
    f32x4 cc = {0.f, 0.f, 0.f, 0.f};
    #pragma unroll
    for (int t = 0; t < K1; ++t) {
      const int m = t % NCH;            // compile-time in unrolled loop
      if (m == 0)
        ca = __builtin_amdgcn_mfma_f32_16x16x32_bf16(af[(pi + t) % K1], wf1[t], ca, 0, 0, 0);
      else if (m == 1)
        cb = __builtin_amdgcn_mfma_f32_16x16x32_bf16(af[(pi + t) % K1], wf1[t], cb, 0, 0, 0);
      else
        cc = __builtin_amdgcn_mfma_f32_16x16x32_bf16(af[(pi + t) % K1], wf1[t], cc, 0, 0, 0);
    }
    if constexpr (K2 > 0) {
      f32x4 cd = {b2, b2, b2, b2};
      #pragma unroll
      for (int t = 0; t < K2; ++t)
        cd = __builtin_amdgcn_mfma_f32_16x16x32_bf16(af[(pi + (KK1 - KK2) + t) % K1], wf2[t], cd, 0, 0, 0);
      #pragma unroll
      for (int r = 0; r < 4; ++r) mx2[r] = fmaxf(mx2[r], cd[r]);
    }
    #pragma unroll
    for (int r = 0; r < 4; ++r) {
      float tot = ca[r] + cb[r];
      if constexpr (NCH == 3) tot += cc[r];
      mx1[r] = fmaxf(mx1[r], tot);
    }
    if (p + pi + 1 < L)
      af[pi] = ldcol(buf, s, cq, p + pi + 5 + KK1);
  };

  __builtin_amdgcn_s_setprio(1);
  int p = 0;
  for (; p + K1 <= L; p += K1) {
    #pragma unroll
    for (int pi = 0; pi < K1; ++pi) body(p, pi);
  }
  #pragma unroll
  for (int pi = 0; pi < K1 - 1; ++pi)
    if (p + pi < L) body(p, pi);
  __builtin_amdgcn_s_setprio(0);

  f32x4 dv = {0.f, 0.f, 0.f, 0.f};
  #pragma unroll
  for (int r = 0; r < 4; ++r) {
    dv[r] = mx1[r] * dv1;
    if constexpr (K2 > 0) dv[r] = fmaf(mx2[r], dv2, dv[r]);
  }
  return dv;
}

// ---- per-role main: weights once, then T-tile double-buffered pipeline ----
template<int K1, int K2>
__device__ __forceinline__ void role_main(
    char* __restrict__ bufA, char* __restrict__ bufB,
    float* __restrict__ redA, float* __restrict__ redB,
    const float* __restrict__ xi, int L, int i, int tile0,
    int tid, int s, int cq, int f,
    const float* __restrict__ wk1, const float* __restrict__ ck1,
    const float* __restrict__ wk2, const float* __restrict__ ck2,
    const float* __restrict__ dw, float* __restrict__ part)
{
  constexpr int KK1 = (K1 - 1) / 2;
  constexpr int KK2 = (K2 > 0) ? (K2 - 1) / 2 : 0;

  // B-operand fragments: ONCE per block (was once per tile).
  bf16x8 wf1[K1];
  #pragma unroll
  for (int t = 0; t < K1; ++t) {
    const float* wp = wk1 + (size_t)((i * 16 + f) * 32 + cq * 8) * K1 + t;
    bf16x8 v;
    #pragma unroll
    for (int j = 0; j < 8; ++j) v[j] = f2bf(wp[(size_t)j * K1]);
    wf1[t] = v;
  }
  bf16x8 wf2[(K2 > 0) ? K2 : 1];
  if constexpr (K2 > 0) {
    #pragma unroll
    for (int t = 0; t < K2; ++t) {
      const float* wp = wk2 + (size_t)((i * 16 + f) * 32 + cq * 8) * K2 + t;
      bf16x8 v;
      #pragma unroll
      for (int j = 0; j < 8; ++j) v[j] = f2bf(wp[(size_t)j * K2]);
      wf2[t] = v;
    }
  }
  const float b1 = ck1[i * 16 + f];
  const float b2 = (K2 > 0) ? ck2[i * 16 + f] : 0.f;
  const float dv1 = dw[(i * 5 + KK1) * 16 + f];
  const float dv2 = (K2 > 0) ? dw[(i * 5 + KK2) * 16 + f] : 0.f;

  StageRegs sr;
  stage_issue(xi, L, tile0 * NS, tid, sr);
  stage_write(bufA, sr);                 // prologue: tile 0 -> bufA
  __syncthreads();                       // tile0 + padding ready

  char* cur = bufA; char* nxt = bufB;
  float* rcur = redA; float* rnxt = redB;
  for (int t = 0; t < T; ++t) {
    if (t + 1 < T) stage_issue(xi, L, (tile0 + t + 1) * NS, tid, sr);  // async
    f32x4 dvec = compute_tile<K1, K2>(cur, s, cq, L, wf1, wf2, b1, b2, dv1, dv2);
    *(f32x4*)&rcur[tid * 4] = dvec;
    if (t + 1 < T) stage_write(nxt, sr); // vmcnt-wait lands here, after compute
    __syncthreads();                     // red ready; next tile staged
    if (tid < 16) {
      float sum = 0.f;
      const int g4 = tid >> 2, r = tid & 3;
      for (int w = 0; w < 3; ++w)
        #pragma unroll
        for (int f2 = 0; f2 < 16; ++f2)
          sum += rcur[(w * 64 + g4 * 16 + f2) * 4 + r];
      part[i * B + (tile0 + t) * NS + tid] = sum;
    }
    { char* tb = cur; cur = nxt; nxt = tb; }
    { float* tr = rcur; rcur = rnxt; rnxt = tr; }
  }
}

// ---- main: grid 1792 = 7 inputs x 256 blocks; block = 4 tiles pipelined ----
__global__ __launch_bounds__(NT) void nettcr_mfma(
    const float* __restrict__ x0, const float* __restrict__ x1,
    const float* __restrict__ x2, const float* __restrict__ x3,
    const float* __restrict__ x4, const float* __restrict__ x5,
    const float* __restrict__ x6,
    const float* __restrict__ w1, const float* __restrict__ c1,
    const float* __restrict__ w3, const float* __restrict__ c3,
    const float* __restrict__ w5, const float* __restrict__ c5,
    const float* __restrict__ w7, const float* __restrict__ c7,
    const float* __restrict__ w9, const float* __restrict__ c9,
    const float* __restrict__ dw,
    float* __restrict__ part)
{
  __shared__ __align__(16) char bufA[TILE_BYTES];
  __shared__ __align__(16) char bufB[TILE_BYTES];
  __shared__ float redA[NT * 4];
  __shared__ float redB[NT * 4];

  const int tid  = threadIdx.x;
  const int lane = tid & 63;
  const int wid  = tid >> 6;
  const int bx   = blockIdx.x;
  const int i    = bx % 7;             // input id (mixes inputs across CUs)
  const int tile0 = (bx / 7) * T;
  const int s    = lane & 15;          // A-side: sample row
  const int cq   = lane >> 4;          // k-quadrant: channels cq*8..+7
  const int f    = lane & 15;          // B-side: filter col

  const float* xi; int L;
  switch (i) {
    case 0: xi = x0; L = 12; break;
    case 1: xi = x1; L = 7;  break;
    case 2: xi = x2; L = 8;  break;
    case 3: xi = x3; L = 22; break;
    case 4: xi = x4; L = 6;  break;
    case 5: xi = x5; L = 7;  break;
    default: xi = x6; L = 23; break;
  }

  // zero SAME-padding columns ONCE per buffer (L fixed per block; data writes
  // never touch q<4 or q>=L+4, so the zeros persist across all T tiles).
  {
    const bf16x8 z = {0, 0, 0, 0, 0, 0, 0, 0};
    for (int e = tid; e < 1024; e += NT) {
      char* bb = (e & 512) ? bufB : bufA;
      const int r  = e & 511;
      const int q8 = r & 7;
      const int q  = (q8 < 4) ? q8 : (L + q8);
      const int cg = (r >> 3) & 3;
      const int ss = r >> 5;
      *(bf16x8*)(bb + (gidx(ss, q, cg) << 4)) = z;
    }
  }

  if (wid == 0)
    role_main<9, 0>(bufA, bufB, redA, redB, xi, L, i, tile0, tid, s, cq, f,
                    w9, c9, nullptr, nullptr, dw, part);
  else if (wid == 1)
    role_main<7, 1>(bufA, bufB, redA, redB, xi, L, i, tile0, tid, s, cq, f,
                    w7, c7, w1, c1, dw, part);
  else
    role_main<5, 3>(bufA, bufB, redA, redB, xi, L, i, tile0, tid, s, cq, f,
                    w5, c5, w3, c3, dw, part);
}

__global__ void combine_sigmoid(const float* __restrict__ part,
                                const float* __restrict__ db,
                                float* __restrict__ out)
{
  const int i = blockIdx.x * blockDim.x + threadIdx.x;
  if (i < B) {
    float sum = db[0];
    #pragma unroll
    for (int j = 0; j < 7; ++j) sum += part[j * B + i];
    out[i] = 1.0f / (1.0f + expf(-sum));
  }
}

} // namespace

extern "C" void kernel_launch(void* const* d_in, const int* in_sizes, int n_in,
                              void* d_out, int out_size, void* d_ws, size_t ws_size,
                              hipStream_t stream) {
  (void)ws_size; (void)out_size;
  const float* xs[7];
  for (int i = 0; i < 7; ++i) xs[i] = (const float*)d_in[i];

  const float* wptr[5] = {nullptr, nullptr, nullptr, nullptr, nullptr};
  const float* cptr[5] = {nullptr, nullptr, nullptr, nullptr, nullptr};
  const float* dw = nullptr;
  const float* db = nullptr;
  int c_seen = 0;
  for (int idx = 7; idx < n_in; ++idx) {
    const int sz = in_sizes[idx];
    const float* p = (const float*)d_in[idx];
    if (sz == 1) { db = p; }
    else if (sz == 16 * 35) { dw = p; }                 // 560
    else if (sz == 7 * 16) { cptr[c_seen++] = p; }      // 112, appear in k order
    else {
      const int k = sz / (7 * 16 * 32);                 // 1,3,5,7,9
      wptr[(k - 1) / 2] = p;
    }
  }

  float* part = (float*)d_ws;   // 7*B floats = 458 KB (per-block partials)

  dim3 grid(7 * (B / NS / T)), block(NT);   // 1792 blocks
  hipLaunchKernelGGL(nettcr_mfma, grid, block, 0, stream,
                     xs[0], xs[1], xs[2], xs[3], xs[4], xs[5], xs[6],
                     wptr[0], cptr[0], wptr[1], cptr[1], wptr[2], cptr[2],
                     wptr[3], cptr[3], wptr[4], cptr[4], dw, part);

  hipLaunchKernelGGL(combine_sigmoid, dim3((B + 255) / 256), dim3(256), 0, stream,
                     part, db, (float*)d_out);
}